// Round 16
// baseline (191.456 us; speedup 1.0000x reference)
//
#include <hip/hip_runtime.h>

#define N_NODES 100000
#define N_EDGES 1600000
#define D 128           // D_IN == D_OUT == 128
#define D4 32           // D in float4 units

#define BM 128                                   // gemm rows per block
#define GEMM_BLOCKS ((N_NODES + BM - 1) / BM)    // 782
#define BUILD_BLOCKS 512                         // edge-list builder blocks
#define TOTAL_BLOCKS (BUILD_BLOCKS + GEMM_BLOCKS)
#define LDK 136                                  // padded LDS row (bf16 elems)

#define G_NODES 32                               // nodes per gather block
#define GATHER_BLOCKS (N_NODES / G_NODES)        // 3125 exact

typedef __attribute__((ext_vector_type(8))) short short8;   // MFMA A/B frag
typedef __attribute__((ext_vector_type(4))) float floatx4;  // MFMA C/D frag

// ---- bf16 helpers ----------------------------------------------------------
__device__ __forceinline__ unsigned short f2bf(float f) {
    unsigned int b = __float_as_uint(f);
    b += 0x7FFFu + ((b >> 16) & 1u);           // RNE
    return (unsigned short)(b >> 16);
}
__device__ __forceinline__ float bf2f(unsigned short u) {
    return __uint_as_float((unsigned int)u << 16);
}

// ---------------------------------------------------------------------------
// Prep (one dispatch): blocks 0..63 -> wt[n*128+k] = bf16(W[k*128+n]);
// blocks 64.. -> head = -1 (200K ints, int4 stores).
// ---------------------------------------------------------------------------
#define PREP_WT_BLOCKS 64
#define PREP_HEAD_BLOCKS ((N_NODES * 2 / 4 + 255) / 256)     // 196
#define PREP_BLOCKS (PREP_WT_BLOCKS + PREP_HEAD_BLOCKS)

__global__ __launch_bounds__(256) void prep(
    const float* __restrict__ W, unsigned short* __restrict__ wt,
    int* __restrict__ head)
{
    if (blockIdx.x < PREP_WT_BLOCKS) {
        int idx = blockIdx.x * 256 + threadIdx.x;   // 0..16383
        int k = idx >> 7, n = idx & 127;
        wt[(size_t)n * D + k] = f2bf(W[idx]);
    } else {
        int i = ((blockIdx.x - PREP_WT_BLOCKS) * 256 + threadIdx.x) * 4;
        if (i < N_NODES * 2)
            *reinterpret_cast<int4*>(head + i) = make_int4(-1, -1, -1, -1);
    }
}

// ---------------------------------------------------------------------------
// Mega kernel, block-specialized (R15-proven):
//   blocks [0, BUILD_BLOCKS): edge list build, TWO sub-chains per node:
//     head[(row<<1) | (tid&1)] -> 200K heads.
//   blocks [BUILD_BLOCKS, ...): MFMA GEMM tile.
// ---------------------------------------------------------------------------
__global__ __launch_bounds__(256, 4) void mega(
    const float* __restrict__ x, const unsigned short* __restrict__ wt,
    unsigned short* __restrict__ sup,
    const int* __restrict__ row, const int* __restrict__ col,
    const float* __restrict__ ew,
    int* __restrict__ head, int4* __restrict__ entries)
{
    __shared__ unsigned short xs[BM * LDK];      // 34.0 KB

    const int tid = threadIdx.x;

    if (blockIdx.x < BUILD_BLOCKS) {
        const int S = BUILD_BLOCKS * 256;        // 131072 (even -> parity const)
        const int par = tid & 1;
        for (int e = blockIdx.x * 256 + tid; e < N_EDGES; e += S) {
            int nx = atomicExch(&head[(row[e] << 1) | par], e);
            entries[e] = make_int4(nx, col[e], __float_as_int(ew[e]), 0);
        }
        return;
    }

    // ---- GEMM path
    const int brow = (blockIdx.x - BUILD_BLOCKS) * BM;

    {
        const float4* xv = reinterpret_cast<const float4*>(x);
        #pragma unroll
        for (int i = 0; i < 16; ++i) {
            int idx = tid + i * 256;             // 0..4095
            int r = idx >> 5, k4 = idx & 31;
            int gr = brow + r;
            float4 v = (gr < N_NODES) ? xv[(size_t)gr * D4 + k4]
                                      : make_float4(0.f, 0.f, 0.f, 0.f);
            ushort4 p;
            p.x = f2bf(v.x); p.y = f2bf(v.y); p.z = f2bf(v.z); p.w = f2bf(v.w);
            *reinterpret_cast<ushort4*>(&xs[r * LDK + k4 * 4]) = p;
        }
    }
    __syncthreads();

    const int wave = tid >> 6;
    const int lane = tid & 63;
    const int l15  = lane & 15;
    const int lkg  = lane >> 4;                  // 0..3

    floatx4 acc[2][8];
    #pragma unroll
    for (int m = 0; m < 2; ++m)
        #pragma unroll
        for (int n = 0; n < 8; ++n) acc[m][n] = (floatx4){0.f, 0.f, 0.f, 0.f};

    const short8* bv = reinterpret_cast<const short8*>(wt);
    const int wrow = wave * 32;
    #pragma unroll
    for (int kk = 0; kk < 4; ++kk) {
        int kb = kk * 32 + lkg * 8;
        short8 a0 = *reinterpret_cast<const short8*>(&xs[(wrow + l15) * LDK + kb]);
        short8 a1 = *reinterpret_cast<const short8*>(&xs[(wrow + 16 + l15) * LDK + kb]);
        #pragma unroll
        for (int n = 0; n < 8; ++n) {
            short8 b = bv[(n * 16 + l15) * 16 + kk * 4 + lkg];
            acc[0][n] = __builtin_amdgcn_mfma_f32_16x16x32_bf16(a0, b, acc[0][n], 0, 0, 0);
            acc[1][n] = __builtin_amdgcn_mfma_f32_16x16x32_bf16(a1, b, acc[1][n], 0, 0, 0);
        }
    }

    const int rbase = brow + wrow + lkg * 4;
    #pragma unroll
    for (int m = 0; m < 2; ++m) {
        #pragma unroll
        for (int r = 0; r < 4; ++r) {
            int grow = rbase + m * 16 + r;
            if (grow < N_NODES) {
                #pragma unroll
                for (int n = 0; n < 8; ++n)
                    sup[(size_t)grow * D + n * 16 + l15] = f2bf(acc[m][n][r]);
            }
        }
    }
}

// ---------------------------------------------------------------------------
// Gather with work-stealing refill: block owns G_NODES nodes; 8 half-waves x
// 2 node-slots (2 sub-chains each -> 4 chases in flight). When a slot's node
// completes, write its out row and pull the next node from the LDS counter.
// Eliminates the lock-step max-of-4 tail waste.
// ---------------------------------------------------------------------------
__global__ __launch_bounds__(256) void gather_refill(
    const int* __restrict__ head, const int4* __restrict__ entries,
    const unsigned short* __restrict__ sup, float* __restrict__ out)
{
    __shared__ int ctr;
    const int tid = threadIdx.x;
    if (tid == 0) ctr = 0;
    __syncthreads();

    const int lane = tid & 31;
    const int src0 = tid & 32;                   // lane-0 of this half-wave
    const int base = blockIdx.x * G_NODES;
    const ushort4* supv = reinterpret_cast<const ushort4*>(sup);
    float4* ov = reinterpret_cast<float4*>(out);

    int nodeA = -1, eA0 = -1, eA1 = -1;
    int nodeB = -1, eB0 = -1, eB1 = -1;
    float4 accA = {0.f, 0.f, 0.f, 0.f};
    float4 accB = accA;
    bool more = true;

    while (true) {
        // refill dead slots (uniform per half-wave)
        if (nodeA < 0 && more) {
            int t = 0;
            if (lane == 0) t = atomicAdd(&ctr, 1);
            int idx = __shfl(t, src0, 64);
            if (idx < G_NODES) {
                nodeA = base + idx;
                int2 h = *reinterpret_cast<const int2*>(head + 2 * nodeA);
                eA0 = h.x; eA1 = h.y;
                accA = make_float4(0.f, 0.f, 0.f, 0.f);
            } else more = false;
        }
        if (nodeB < 0 && more) {
            int t = 0;
            if (lane == 0) t = atomicAdd(&ctr, 1);
            int idx = __shfl(t, src0, 64);
            if (idx < G_NODES) {
                nodeB = base + idx;
                int2 h = *reinterpret_cast<const int2*>(head + 2 * nodeB);
                eB0 = h.x; eB1 = h.y;
                accB = make_float4(0.f, 0.f, 0.f, 0.f);
            } else more = false;
        }
        if (nodeA < 0 && nodeB < 0) break;

        // one chase step: 4 entry loads + 4 support rows in flight
        int4 qa0 = entries[eA0 >= 0 ? eA0 : 0];
        int4 qa1 = entries[eA1 >= 0 ? eA1 : 0];
        int4 qb0 = entries[eB0 >= 0 ? eB0 : 0];
        int4 qb1 = entries[eB1 >= 0 ? eB1 : 0];

        ushort4 sa0 = supv[(size_t)qa0.y * D4 + lane];
        ushort4 sa1 = supv[(size_t)qa1.y * D4 + lane];
        ushort4 sb0 = supv[(size_t)qb0.y * D4 + lane];
        ushort4 sb1 = supv[(size_t)qb1.y * D4 + lane];

        float wa0 = (eA0 >= 0) ? __int_as_float(qa0.z) : 0.f;
        float wa1 = (eA1 >= 0) ? __int_as_float(qa1.z) : 0.f;
        float wb0 = (eB0 >= 0) ? __int_as_float(qb0.z) : 0.f;
        float wb1 = (eB1 >= 0) ? __int_as_float(qb1.z) : 0.f;

        accA.x = fmaf(wa0, bf2f(sa0.x), accA.x); accA.x = fmaf(wa1, bf2f(sa1.x), accA.x);
        accA.y = fmaf(wa0, bf2f(sa0.y), accA.y); accA.y = fmaf(wa1, bf2f(sa1.y), accA.y);
        accA.z = fmaf(wa0, bf2f(sa0.z), accA.z); accA.z = fmaf(wa1, bf2f(sa1.z), accA.z);
        accA.w = fmaf(wa0, bf2f(sa0.w), accA.w); accA.w = fmaf(wa1, bf2f(sa1.w), accA.w);
        accB.x = fmaf(wb0, bf2f(sb0.x), accB.x); accB.x = fmaf(wb1, bf2f(sb1.x), accB.x);
        accB.y = fmaf(wb0, bf2f(sb0.y), accB.y); accB.y = fmaf(wb1, bf2f(sb1.y), accB.y);
        accB.z = fmaf(wb0, bf2f(sb0.z), accB.z); accB.z = fmaf(wb1, bf2f(sb1.z), accB.z);
        accB.w = fmaf(wb0, bf2f(sb0.w), accB.w); accB.w = fmaf(wb1, bf2f(sb1.w), accB.w);

        eA0 = (eA0 >= 0) ? qa0.x : -1;
        eA1 = (eA1 >= 0) ? qa1.x : -1;
        eB0 = (eB0 >= 0) ? qb0.x : -1;
        eB1 = (eB1 >= 0) ? qb1.x : -1;

        // completion: write row, free the slot (uniform per half-wave)
        if (nodeA >= 0 && eA0 < 0 && eA1 < 0) {
            ov[(size_t)nodeA * D4 + lane] = accA;
            nodeA = -1;
        }
        if (nodeB >= 0 && eB0 < 0 && eB1 < 0) {
            ov[(size_t)nodeB * D4 + lane] = accB;
            nodeB = -1;
        }
    }
}

// ---------------------------------------------------------------------------
// Fallback path (ws too small): VALU gemm + atomic scatter (proven R3/R8).
// ---------------------------------------------------------------------------
__device__ __forceinline__ void fma4(float4& a, float s, const float4& b) {
    a.x = fmaf(s, b.x, a.x);
    a.y = fmaf(s, b.y, a.y);
    a.z = fmaf(s, b.z, a.z);
    a.w = fmaf(s, b.w, a.w);
}

__global__ __launch_bounds__(256) void gemm_xw(
    const float* __restrict__ x, const float* __restrict__ W,
    unsigned short* __restrict__ sup)
{
    __shared__ float4 xs[32 * D4];
    const int tid = threadIdx.x;
    const int block_row = blockIdx.x * 32;

    const float4* xv = reinterpret_cast<const float4*>(x) + (size_t)block_row * D4;
    #pragma unroll
    for (int i = 0; i < 4; ++i) xs[tid + i * 256] = xv[tid + i * 256];
    __syncthreads();

    const int cg = tid & 31;
    const int rg = tid >> 5;
    const float4* Wv = reinterpret_cast<const float4*>(W);

    float4 acc0 = {0.f, 0.f, 0.f, 0.f};
    float4 acc1 = acc0, acc2 = acc0, acc3 = acc0;

    const int r0 = rg * 4;
    #pragma unroll 8
    for (int k4 = 0; k4 < D4; ++k4) {
        float4 xa = xs[(r0 + 0) * D4 + k4];
        float4 xb = xs[(r0 + 1) * D4 + k4];
        float4 xc = xs[(r0 + 2) * D4 + k4];
        float4 xd = xs[(r0 + 3) * D4 + k4];
        float4 w0 = Wv[(k4 * 4 + 0) * D4 + cg];
        fma4(acc0, xa.x, w0); fma4(acc1, xb.x, w0);
        fma4(acc2, xc.x, w0); fma4(acc3, xd.x, w0);
        float4 w1 = Wv[(k4 * 4 + 1) * D4 + cg];
        fma4(acc0, xa.y, w1); fma4(acc1, xb.y, w1);
        fma4(acc2, xc.y, w1); fma4(acc3, xd.y, w1);
        float4 w2 = Wv[(k4 * 4 + 2) * D4 + cg];
        fma4(acc0, xa.z, w2); fma4(acc1, xb.z, w2);
        fma4(acc2, xc.z, w2); fma4(acc3, xd.z, w2);
        float4 w3 = Wv[(k4 * 4 + 3) * D4 + cg];
        fma4(acc0, xa.w, w3); fma4(acc1, xb.w, w3);
        fma4(acc2, xc.w, w3); fma4(acc3, xd.w, w3);
    }

    ushort4 p;
    #define STORE_BF16(ACC, R)                                            \
        p.x = f2bf(ACC.x); p.y = f2bf(ACC.y);                             \
        p.z = f2bf(ACC.z); p.w = f2bf(ACC.w);                             \
        *reinterpret_cast<ushort4*>(sup + (size_t)(block_row + r0 + R) * D + cg * 4) = p;
    STORE_BF16(acc0, 0)
    STORE_BF16(acc1, 1)
    STORE_BF16(acc2, 2)
    STORE_BF16(acc3, 3)
    #undef STORE_BF16
}

__global__ __launch_bounds__(256) void scatter_edges(
    const int* __restrict__ row, const int* __restrict__ col,
    const float* __restrict__ ew, const unsigned short* __restrict__ sup,
    float* __restrict__ out)
{
    const int e = blockIdx.x * 8 + (threadIdx.x >> 5);
    if (e >= N_EDGES) return;
    const int lane = threadIdx.x & 31;

    const int r = row[e];
    const int c = col[e];
    const float w = ew[e];
    ushort4 s = reinterpret_cast<const ushort4*>(sup + (size_t)c * D)[lane];
    float* o = out + (size_t)r * D + lane * 4;
    atomicAdd(o + 0, w * bf2f(s.x));
    atomicAdd(o + 1, w * bf2f(s.y));
    atomicAdd(o + 2, w * bf2f(s.z));
    atomicAdd(o + 3, w * bf2f(s.w));
}

extern "C" void kernel_launch(void* const* d_in, const int* in_sizes, int n_in,
                              void* d_out, int out_size, void* d_ws, size_t ws_size,
                              hipStream_t stream)
{
    const float* x      = (const float*)d_in[0];   // [N_NODES, 128]
    const int*   row    = (const int*)d_in[1];     // [N_EDGES]
    const int*   col    = (const int*)d_in[2];     // [N_EDGES]
    const float* ew     = (const float*)d_in[3];   // [N_EDGES]
    const float* weight = (const float*)d_in[4];   // [128, 128]
    float* out = (float*)d_out;                    // [N_NODES, 128]

    char* ws = (char*)d_ws;
    const size_t off_sup     = 0;                                      // 25.6 MB
    const size_t off_head    = off_sup + (size_t)N_NODES * D * 2;      // 800 KB (2 chains/node)
    const size_t off_entries = off_head + (((size_t)N_NODES * 8 + 15) & ~(size_t)15);
    const size_t off_wt      = off_entries + (size_t)N_EDGES * 16;     // 32 KB
    const size_t required    = off_wt + (size_t)D * D * 2;

    unsigned short* sup = (unsigned short*)(ws + off_sup);

    if (ws_size >= required) {
        int*  head    = (int*)(ws + off_head);
        int4* entries = (int4*)(ws + off_entries);
        unsigned short* wt = (unsigned short*)(ws + off_wt);

        // prep: wt conversion + head = -1 (one dispatch)
        prep<<<PREP_BLOCKS, 256, 0, stream>>>(weight, wt, head);

        // block-specialized: builders (first) + MFMA gemm tiles, overlapped
        mega<<<TOTAL_BLOCKS, 256, 0, stream>>>(
            x, wt, sup, row, col, ew, head, entries);

        // gather: work-stealing refill, writes every output row
        gather_refill<<<GATHER_BLOCKS, 256, 0, stream>>>(head, entries, sup, out);
    } else {
        gemm_xw<<<N_NODES / 32, 256, 0, stream>>>(x, weight, sup);
        hipMemsetAsync(d_out, 0, (size_t)N_NODES * D * sizeof(float), stream);
        scatter_edges<<<N_EDGES / 8, 256, 0, stream>>>(row, col, ew, sup, out);
    }
}

// Round 17
// 177.411 us; speedup vs baseline: 1.0792x; 1.0792x over previous
//
#include <hip/hip_runtime.h>

#define N_NODES 100000
#define N_EDGES 1600000
#define D 128           // D_IN == D_OUT == 128
#define D4 32           // D in float4 units

#define BM 64                                    // gemm rows per block
#define GEMM_BLOCKS ((N_NODES + BM - 1) / BM)    // 1563 (tail zero-padded)
#define BUILD_BLOCKS 512                         // edge-list builder blocks
#define TOTAL_BLOCKS (BUILD_BLOCKS + GEMM_BLOCKS)
#define LDK 136                                  // padded LDS row (bf16 elems)

#define GATHER_BLOCKS (N_NODES / 16)             // 6250 exact

typedef __attribute__((ext_vector_type(8))) short short8;   // MFMA A/B frag
typedef __attribute__((ext_vector_type(4))) float floatx4;  // MFMA C/D frag

// ---- bf16 helpers ----------------------------------------------------------
__device__ __forceinline__ unsigned short f2bf(float f) {
    unsigned int b = __float_as_uint(f);
    b += 0x7FFFu + ((b >> 16) & 1u);           // RNE
    return (unsigned short)(b >> 16);
}
__device__ __forceinline__ float bf2f(unsigned short u) {
    return __uint_as_float((unsigned int)u << 16);
}

// ---------------------------------------------------------------------------
// Prep (one dispatch): blocks 0..63 -> wt[n*128+k] = bf16(W[k*128+n]);
// blocks 64.. -> head = -1 (200K ints, int4 stores).
// ---------------------------------------------------------------------------
#define PREP_WT_BLOCKS 64
#define PREP_HEAD_BLOCKS ((N_NODES * 2 / 4 + 255) / 256)     // 196
#define PREP_BLOCKS (PREP_WT_BLOCKS + PREP_HEAD_BLOCKS)

__global__ __launch_bounds__(256) void prep(
    const float* __restrict__ W, unsigned short* __restrict__ wt,
    int* __restrict__ head)
{
    if (blockIdx.x < PREP_WT_BLOCKS) {
        int idx = blockIdx.x * 256 + threadIdx.x;   // 0..16383
        int k = idx >> 7, n = idx & 127;
        wt[(size_t)n * D + k] = f2bf(W[idx]);
    } else {
        int i = ((blockIdx.x - PREP_WT_BLOCKS) * 256 + threadIdx.x) * 4;
        if (i < N_NODES * 2)
            *reinterpret_cast<int4*>(head + i) = make_int4(-1, -1, -1, -1);
    }
}

// ---------------------------------------------------------------------------
// Mega kernel, block-specialized:
//   blocks [0, BUILD_BLOCKS): edge list build (R15-proven simple loop),
//     TWO sub-chains per node: head[(row<<1) | (tid&1)].
//   blocks [BUILD_BLOCKS, ...): MFMA GEMM, BM=64: xs = 17 KB -> 8 blocks/CU
//     (32 waves/CU, 2x R15's latency hiding for global B-frag loads).
//     Wave tiling 2x2: wave w -> rows (w&1)*32..+32, cols (w>>1)*64..+64
//     (2 m-frags x 4 n-frags, B-reuse 2:1).
// ---------------------------------------------------------------------------
__global__ __launch_bounds__(256, 8) void mega(
    const float* __restrict__ x, const unsigned short* __restrict__ wt,
    unsigned short* __restrict__ sup,
    const int* __restrict__ row, const int* __restrict__ col,
    const float* __restrict__ ew,
    int* __restrict__ head, int4* __restrict__ entries)
{
    __shared__ unsigned short xs[BM * LDK];      // 17.0 KB

    const int tid = threadIdx.x;

    if (blockIdx.x < BUILD_BLOCKS) {
        const int S = BUILD_BLOCKS * 256;        // 131072 (even -> parity const)
        const int par = tid & 1;
        for (int e = blockIdx.x * 256 + tid; e < N_EDGES; e += S) {
            int nx = atomicExch(&head[(row[e] << 1) | par], e);
            entries[e] = make_int4(nx, col[e], __float_as_int(ew[e]), 0);
        }
        return;
    }

    // ---- GEMM path
    const int brow = (blockIdx.x - BUILD_BLOCKS) * BM;

    // stage x tile (fp32 -> bf16), 64 rows x 32 float4, zero-pad tail rows
    {
        const float4* xv = reinterpret_cast<const float4*>(x);
        #pragma unroll
        for (int i = 0; i < 8; ++i) {
            int idx = tid + i * 256;             // 0..2047
            int r = idx >> 5, k4 = idx & 31;
            int gr = brow + r;
            float4 v = (gr < N_NODES) ? xv[(size_t)gr * D4 + k4]
                                      : make_float4(0.f, 0.f, 0.f, 0.f);
            ushort4 p;
            p.x = f2bf(v.x); p.y = f2bf(v.y); p.z = f2bf(v.z); p.w = f2bf(v.w);
            *reinterpret_cast<ushort4*>(&xs[r * LDK + k4 * 4]) = p;
        }
    }
    __syncthreads();

    const int wave = tid >> 6;
    const int lane = tid & 63;
    const int l15  = lane & 15;
    const int lkg  = lane >> 4;                  // 0..3
    const int wr   = (wave & 1) * 32;            // row half
    const int wc   = (wave >> 1) * 64;           // col half

    floatx4 acc[2][4];
    #pragma unroll
    for (int m = 0; m < 2; ++m)
        #pragma unroll
        for (int n = 0; n < 4; ++n) acc[m][n] = (floatx4){0.f, 0.f, 0.f, 0.f};

    const short8* bv = reinterpret_cast<const short8*>(wt);
    #pragma unroll
    for (int kk = 0; kk < 4; ++kk) {
        int kb = kk * 32 + lkg * 8;
        short8 a0 = *reinterpret_cast<const short8*>(&xs[(wr + l15) * LDK + kb]);
        short8 a1 = *reinterpret_cast<const short8*>(&xs[(wr + 16 + l15) * LDK + kb]);
        #pragma unroll
        for (int n = 0; n < 4; ++n) {
            // B frag: col = wc + n*16 + l15, k-range kb..kb+7 (W^T row-major)
            short8 b = bv[(wc + n * 16 + l15) * 16 + kk * 4 + lkg];
            acc[0][n] = __builtin_amdgcn_mfma_f32_16x16x32_bf16(a0, b, acc[0][n], 0, 0, 0);
            acc[1][n] = __builtin_amdgcn_mfma_f32_16x16x32_bf16(a1, b, acc[1][n], 0, 0, 0);
        }
    }

    // epilogue: D col = lane&15, row = (lane>>4)*4 + r  (m89-verified)
    const int rbase = brow + wr + lkg * 4;
    #pragma unroll
    for (int m = 0; m < 2; ++m) {
        #pragma unroll
        for (int r = 0; r < 4; ++r) {
            int grow = rbase + m * 16 + r;
            if (grow < N_NODES) {
                #pragma unroll
                for (int n = 0; n < 4; ++n)
                    sup[(size_t)grow * D + wc + n * 16 + l15] = f2bf(acc[m][n][r]);
            }
        }
    }
}

// ---------------------------------------------------------------------------
// Gather (R15-proven, 96.4 us): half-wave owns 2 nodes = 4 sub-chains,
// interleaved -> 4 independent pointer-chases in flight.
// ---------------------------------------------------------------------------
__global__ __launch_bounds__(256) void gather_list(
    const int* __restrict__ head, const int4* __restrict__ entries,
    const unsigned short* __restrict__ sup, float* __restrict__ out)
{
    const int half = threadIdx.x >> 5;          // 0..7
    const int lane = threadIdx.x & 31;
    const int nb = blockIdx.x * 16 + half * 2;  // 2 nodes per half-wave

    int4 h = *reinterpret_cast<const int4*>(head + 2 * nb);
    int e0 = h.x, e1 = h.y, e2 = h.z, e3 = h.w;

    float4 A0 = {0.f, 0.f, 0.f, 0.f};
    float4 A1 = A0, A2 = A0, A3 = A0;

    while (e0 >= 0 || e1 >= 0 || e2 >= 0 || e3 >= 0) {
        int4 q0 = entries[e0 >= 0 ? e0 : 0];
        int4 q1 = entries[e1 >= 0 ? e1 : 0];
        int4 q2 = entries[e2 >= 0 ? e2 : 0];
        int4 q3 = entries[e3 >= 0 ? e3 : 0];

        ushort4 s0 = reinterpret_cast<const ushort4*>(sup + (size_t)q0.y * D)[lane];
        ushort4 s1 = reinterpret_cast<const ushort4*>(sup + (size_t)q1.y * D)[lane];
        ushort4 s2 = reinterpret_cast<const ushort4*>(sup + (size_t)q2.y * D)[lane];
        ushort4 s3 = reinterpret_cast<const ushort4*>(sup + (size_t)q3.y * D)[lane];

        float w0 = (e0 >= 0) ? __int_as_float(q0.z) : 0.f;
        float w1 = (e1 >= 0) ? __int_as_float(q1.z) : 0.f;
        float w2 = (e2 >= 0) ? __int_as_float(q2.z) : 0.f;
        float w3 = (e3 >= 0) ? __int_as_float(q3.z) : 0.f;

        A0.x = fmaf(w0, bf2f(s0.x), A0.x); A0.y = fmaf(w0, bf2f(s0.y), A0.y);
        A0.z = fmaf(w0, bf2f(s0.z), A0.z); A0.w = fmaf(w0, bf2f(s0.w), A0.w);
        A1.x = fmaf(w1, bf2f(s1.x), A1.x); A1.y = fmaf(w1, bf2f(s1.y), A1.y);
        A1.z = fmaf(w1, bf2f(s1.z), A1.z); A1.w = fmaf(w1, bf2f(s1.w), A1.w);
        A2.x = fmaf(w2, bf2f(s2.x), A2.x); A2.y = fmaf(w2, bf2f(s2.y), A2.y);
        A2.z = fmaf(w2, bf2f(s2.z), A2.z); A2.w = fmaf(w2, bf2f(s2.w), A2.w);
        A3.x = fmaf(w3, bf2f(s3.x), A3.x); A3.y = fmaf(w3, bf2f(s3.y), A3.y);
        A3.z = fmaf(w3, bf2f(s3.z), A3.z); A3.w = fmaf(w3, bf2f(s3.w), A3.w);

        e0 = (e0 >= 0) ? q0.x : -1;
        e1 = (e1 >= 0) ? q1.x : -1;
        e2 = (e2 >= 0) ? q2.x : -1;
        e3 = (e3 >= 0) ? q3.x : -1;
    }

    float4 a0, a1;
    a0.x = A0.x + A1.x; a0.y = A0.y + A1.y; a0.z = A0.z + A1.z; a0.w = A0.w + A1.w;
    a1.x = A2.x + A3.x; a1.y = A2.y + A3.y; a1.z = A2.z + A3.z; a1.w = A2.w + A3.w;

    float4* ov = reinterpret_cast<float4*>(out);
    ov[(size_t)(nb + 0) * D4 + lane] = a0;
    ov[(size_t)(nb + 1) * D4 + lane] = a1;
}

// ---------------------------------------------------------------------------
// Fallback path (ws too small): VALU gemm + atomic scatter (proven R3/R8).
// ---------------------------------------------------------------------------
__device__ __forceinline__ void fma4(float4& a, float s, const float4& b) {
    a.x = fmaf(s, b.x, a.x);
    a.y = fmaf(s, b.y, a.y);
    a.z = fmaf(s, b.z, a.z);
    a.w = fmaf(s, b.w, a.w);
}

__global__ __launch_bounds__(256) void gemm_xw(
    const float* __restrict__ x, const float* __restrict__ W,
    unsigned short* __restrict__ sup)
{
    __shared__ float4 xs[32 * D4];
    const int tid = threadIdx.x;
    const int block_row = blockIdx.x * 32;

    const float4* xv = reinterpret_cast<const float4*>(x) + (size_t)block_row * D4;
    #pragma unroll
    for (int i = 0; i < 4; ++i) xs[tid + i * 256] = xv[tid + i * 256];
    __syncthreads();

    const int cg = tid & 31;
    const int rg = tid >> 5;
    const float4* Wv = reinterpret_cast<const float4*>(W);

    float4 acc0 = {0.f, 0.f, 0.f, 0.f};
    float4 acc1 = acc0, acc2 = acc0, acc3 = acc0;

    const int r0 = rg * 4;
    #pragma unroll 8
    for (int k4 = 0; k4 < D4; ++k4) {
        float4 xa = xs[(r0 + 0) * D4 + k4];
        float4 xb = xs[(r0 + 1) * D4 + k4];
        float4 xc = xs[(r0 + 2) * D4 + k4];
        float4 xd = xs[(r0 + 3) * D4 + k4];
        float4 w0 = Wv[(k4 * 4 + 0) * D4 + cg];
        fma4(acc0, xa.x, w0); fma4(acc1, xb.x, w0);
        fma4(acc2, xc.x, w0); fma4(acc3, xd.x, w0);
        float4 w1 = Wv[(k4 * 4 + 1) * D4 + cg];
        fma4(acc0, xa.y, w1); fma4(acc1, xb.y, w1);
        fma4(acc2, xc.y, w1); fma4(acc3, xd.y, w1);
        float4 w2 = Wv[(k4 * 4 + 2) * D4 + cg];
        fma4(acc0, xa.z, w2); fma4(acc1, xb.z, w2);
        fma4(acc2, xc.z, w2); fma4(acc3, xd.z, w2);
        float4 w3 = Wv[(k4 * 4 + 3) * D4 + cg];
        fma4(acc0, xa.w, w3); fma4(acc1, xb.w, w3);
        fma4(acc2, xc.w, w3); fma4(acc3, xd.w, w3);
    }

    ushort4 p;
    #define STORE_BF16(ACC, R)                                            \
        p.x = f2bf(ACC.x); p.y = f2bf(ACC.y);                             \
        p.z = f2bf(ACC.z); p.w = f2bf(ACC.w);                             \
        *reinterpret_cast<ushort4*>(sup + (size_t)(block_row + r0 + R) * D + cg * 4) = p;
    STORE_BF16(acc0, 0)
    STORE_BF16(acc1, 1)
    STORE_BF16(acc2, 2)
    STORE_BF16(acc3, 3)
    #undef STORE_BF16
}

__global__ __launch_bounds__(256) void scatter_edges(
    const int* __restrict__ row, const int* __restrict__ col,
    const float* __restrict__ ew, const unsigned short* __restrict__ sup,
    float* __restrict__ out)
{
    const int e = blockIdx.x * 8 + (threadIdx.x >> 5);
    if (e >= N_EDGES) return;
    const int lane = threadIdx.x & 31;

    const int r = row[e];
    const int c = col[e];
    const float w = ew[e];
    ushort4 s = reinterpret_cast<const ushort4*>(sup + (size_t)c * D)[lane];
    float* o = out + (size_t)r * D + lane * 4;
    atomicAdd(o + 0, w * bf2f(s.x));
    atomicAdd(o + 1, w * bf2f(s.y));
    atomicAdd(o + 2, w * bf2f(s.z));
    atomicAdd(o + 3, w * bf2f(s.w));
}

extern "C" void kernel_launch(void* const* d_in, const int* in_sizes, int n_in,
                              void* d_out, int out_size, void* d_ws, size_t ws_size,
                              hipStream_t stream)
{
    const float* x      = (const float*)d_in[0];   // [N_NODES, 128]
    const int*   row    = (const int*)d_in[1];     // [N_EDGES]
    const int*   col    = (const int*)d_in[2];     // [N_EDGES]
    const float* ew     = (const float*)d_in[3];   // [N_EDGES]
    const float* weight = (const float*)d_in[4];   // [128, 128]
    float* out = (float*)d_out;                    // [N_NODES, 128]

    char* ws = (char*)d_ws;
    const size_t off_sup     = 0;                                      // 25.6 MB
    const size_t off_head    = off_sup + (size_t)N_NODES * D * 2;      // 800 KB (2 chains/node)
    const size_t off_entries = off_head + (((size_t)N_NODES * 8 + 15) & ~(size_t)15);
    const size_t off_wt      = off_entries + (size_t)N_EDGES * 16;     // 32 KB
    const size_t required    = off_wt + (size_t)D * D * 2;

    unsigned short* sup = (unsigned short*)(ws + off_sup);

    if (ws_size >= required) {
        int*  head    = (int*)(ws + off_head);
        int4* entries = (int4*)(ws + off_entries);
        unsigned short* wt = (unsigned short*)(ws + off_wt);

        // prep: wt conversion + head = -1 (one dispatch)
        prep<<<PREP_BLOCKS, 256, 0, stream>>>(weight, wt, head);

        // block-specialized: builders (first) + MFMA gemm tiles, overlapped
        mega<<<TOTAL_BLOCKS, 256, 0, stream>>>(
            x, wt, sup, row, col, ew, head, entries);

        // gather: writes every output row (no out memset needed)
        gather_list<<<GATHER_BLOCKS, 256, 0, stream>>>(head, entries, sup, out);
    } else {
        gemm_xw<<<N_NODES / 32, 256, 0, stream>>>(x, weight, sup);
        hipMemsetAsync(d_out, 0, (size_t)N_NODES * D * sizeof(float), stream);
        scatter_edges<<<N_EDGES / 8, 256, 0, stream>>>(row, col, ew, sup, out);
    }
}

// Round 18
// 175.815 us; speedup vs baseline: 1.0890x; 1.0091x over previous
//
#include <hip/hip_runtime.h>

#define N_NODES 100000
#define N_EDGES 1600000
#define D 128           // D_IN == D_OUT == 128
#define D4 32           // D in float4 units

#define BM 64                                    // gemm rows per block
#define GEMM_BLOCKS ((N_NODES + BM - 1) / BM)    // 1563 (tail zero-padded)
#define BUILD_BLOCKS 512                         // edge-list builder blocks
#define TOTAL_BLOCKS (BUILD_BLOCKS + GEMM_BLOCKS)
#define LDK 136                                  // padded LDS row (bf16 elems)

#define GATHER_BLOCKS (N_NODES / 16)             // 6250 exact

typedef __attribute__((ext_vector_type(8))) short short8;   // MFMA A/B frag
typedef __attribute__((ext_vector_type(4))) float floatx4;  // MFMA C/D frag
typedef unsigned long long u64;

// packed edge entry: col[0:17) | next[17:38) | bf16(w)[48:64)
#define NEXT_END 0x1FFFFF

// ---- bf16 helpers ----------------------------------------------------------
__device__ __forceinline__ unsigned short f2bf(float f) {
    unsigned int b = __float_as_uint(f);
    b += 0x7FFFu + ((b >> 16) & 1u);           // RNE
    return (unsigned short)(b >> 16);
}
__device__ __forceinline__ float bf2f(unsigned short u) {
    return __uint_as_float((unsigned int)u << 16);
}

// ---------------------------------------------------------------------------
// Prep (one dispatch): blocks 0..63 -> wt[n*128+k] = bf16(W[k*128+n]);
// blocks 64.. -> head = -1 (200K ints, int4 stores).
// ---------------------------------------------------------------------------
#define PREP_WT_BLOCKS 64
#define PREP_HEAD_BLOCKS ((N_NODES * 2 / 4 + 255) / 256)     // 196
#define PREP_BLOCKS (PREP_WT_BLOCKS + PREP_HEAD_BLOCKS)

__global__ __launch_bounds__(256) void prep(
    const float* __restrict__ W, unsigned short* __restrict__ wt,
    int* __restrict__ head)
{
    if (blockIdx.x < PREP_WT_BLOCKS) {
        int idx = blockIdx.x * 256 + threadIdx.x;   // 0..16383
        int k = idx >> 7, n = idx & 127;
        wt[(size_t)n * D + k] = f2bf(W[idx]);
    } else {
        int i = ((blockIdx.x - PREP_WT_BLOCKS) * 256 + threadIdx.x) * 4;
        if (i < N_NODES * 2)
            *reinterpret_cast<int4*>(head + i) = make_int4(-1, -1, -1, -1);
    }
}

// ---------------------------------------------------------------------------
// Mega kernel, block-specialized:
//   blocks [0, BUILD_BLOCKS): edge list build, TWO sub-chains per node:
//     head[(row<<1) | (tid&1)]. Entries packed to 8 B, nontemporal store.
//   blocks [BUILD_BLOCKS, ...): MFMA GEMM, BM=64 (8 blocks/CU).
// ---------------------------------------------------------------------------
__global__ __launch_bounds__(256, 8) void mega(
    const float* __restrict__ x, const unsigned short* __restrict__ wt,
    unsigned short* __restrict__ sup,
    const int* __restrict__ row, const int* __restrict__ col,
    const float* __restrict__ ew,
    int* __restrict__ head, u64* __restrict__ entries)
{
    __shared__ unsigned short xs[BM * LDK];      // 17.0 KB

    const int tid = threadIdx.x;

    if (blockIdx.x < BUILD_BLOCKS) {
        const int S = BUILD_BLOCKS * 256;        // 131072 (even -> parity const)
        const int par = tid & 1;
        for (int e = blockIdx.x * 256 + tid; e < N_EDGES; e += S) {
            int nx = atomicExch(&head[(row[e] << 1) | par], e);
            u64 v = (u64)(unsigned)col[e]
                  | ((u64)((unsigned)nx & 0x1FFFFFu) << 17)
                  | ((u64)f2bf(ew[e]) << 48);
            __builtin_nontemporal_store(v, &entries[e]);
        }
        return;
    }

    // ---- GEMM path
    const int brow = (blockIdx.x - BUILD_BLOCKS) * BM;

    // stage x tile (fp32 -> bf16), 64 rows x 32 float4, zero-pad tail rows
    {
        const float4* xv = reinterpret_cast<const float4*>(x);
        #pragma unroll
        for (int i = 0; i < 8; ++i) {
            int idx = tid + i * 256;             // 0..2047
            int r = idx >> 5, k4 = idx & 31;
            int gr = brow + r;
            float4 v = (gr < N_NODES) ? xv[(size_t)gr * D4 + k4]
                                      : make_float4(0.f, 0.f, 0.f, 0.f);
            ushort4 p;
            p.x = f2bf(v.x); p.y = f2bf(v.y); p.z = f2bf(v.z); p.w = f2bf(v.w);
            *reinterpret_cast<ushort4*>(&xs[r * LDK + k4 * 4]) = p;
        }
    }
    __syncthreads();

    const int wave = tid >> 6;
    const int lane = tid & 63;
    const int l15  = lane & 15;
    const int lkg  = lane >> 4;                  // 0..3
    const int wr   = (wave & 1) * 32;            // row half
    const int wc   = (wave >> 1) * 64;           // col half

    floatx4 acc[2][4];
    #pragma unroll
    for (int m = 0; m < 2; ++m)
        #pragma unroll
        for (int n = 0; n < 4; ++n) acc[m][n] = (floatx4){0.f, 0.f, 0.f, 0.f};

    const short8* bv = reinterpret_cast<const short8*>(wt);
    #pragma unroll
    for (int kk = 0; kk < 4; ++kk) {
        int kb = kk * 32 + lkg * 8;
        short8 a0 = *reinterpret_cast<const short8*>(&xs[(wr + l15) * LDK + kb]);
        short8 a1 = *reinterpret_cast<const short8*>(&xs[(wr + 16 + l15) * LDK + kb]);
        #pragma unroll
        for (int n = 0; n < 4; ++n) {
            short8 b = bv[(wc + n * 16 + l15) * 16 + kk * 4 + lkg];
            acc[0][n] = __builtin_amdgcn_mfma_f32_16x16x32_bf16(a0, b, acc[0][n], 0, 0, 0);
            acc[1][n] = __builtin_amdgcn_mfma_f32_16x16x32_bf16(a1, b, acc[1][n], 0, 0, 0);
        }
    }

    // epilogue: D col = lane&15, row = (lane>>4)*4 + r  (m89-verified)
    const int rbase = brow + wr + lkg * 4;
    #pragma unroll
    for (int m = 0; m < 2; ++m) {
        #pragma unroll
        for (int r = 0; r < 4; ++r) {
            int grow = rbase + m * 16 + r;
            if (grow < N_NODES) {
                #pragma unroll
                for (int n = 0; n < 4; ++n)
                    sup[(size_t)grow * D + wc + n * 16 + l15] = f2bf(acc[m][n][r]);
            }
        }
    }
}

// ---------------------------------------------------------------------------
// Gather (R15 structure, packed entries): half-wave owns 2 nodes = 4
// sub-chains, interleaved -> 4 independent pointer-chases in flight.
// Per edge: one 8 B entry load + 256 B support row.
// ---------------------------------------------------------------------------
__global__ __launch_bounds__(256) void gather_list(
    const int* __restrict__ head, const u64* __restrict__ entries,
    const unsigned short* __restrict__ sup, float* __restrict__ out)
{
    const int half = threadIdx.x >> 5;          // 0..7
    const int lane = threadIdx.x & 31;
    const int nb = blockIdx.x * 16 + half * 2;  // 2 nodes per half-wave

    int4 h = *reinterpret_cast<const int4*>(head + 2 * nb);
    int e0 = h.x, e1 = h.y, e2 = h.z, e3 = h.w;

    float4 A0 = {0.f, 0.f, 0.f, 0.f};
    float4 A1 = A0, A2 = A0, A3 = A0;

    while (e0 >= 0 || e1 >= 0 || e2 >= 0 || e3 >= 0) {
        u64 q0 = entries[e0 >= 0 ? e0 : 0];
        u64 q1 = entries[e1 >= 0 ? e1 : 0];
        u64 q2 = entries[e2 >= 0 ? e2 : 0];
        u64 q3 = entries[e3 >= 0 ? e3 : 0];

        int c0 = (int)(q0 & 0x1FFFF);
        int c1 = (int)(q1 & 0x1FFFF);
        int c2 = (int)(q2 & 0x1FFFF);
        int c3 = (int)(q3 & 0x1FFFF);

        ushort4 s0 = reinterpret_cast<const ushort4*>(sup + (size_t)c0 * D)[lane];
        ushort4 s1 = reinterpret_cast<const ushort4*>(sup + (size_t)c1 * D)[lane];
        ushort4 s2 = reinterpret_cast<const ushort4*>(sup + (size_t)c2 * D)[lane];
        ushort4 s3 = reinterpret_cast<const ushort4*>(sup + (size_t)c3 * D)[lane];

        float w0 = (e0 >= 0) ? __uint_as_float((unsigned)(q0 >> 32) & 0xFFFF0000u) : 0.f;
        float w1 = (e1 >= 0) ? __uint_as_float((unsigned)(q1 >> 32) & 0xFFFF0000u) : 0.f;
        float w2 = (e2 >= 0) ? __uint_as_float((unsigned)(q2 >> 32) & 0xFFFF0000u) : 0.f;
        float w3 = (e3 >= 0) ? __uint_as_float((unsigned)(q3 >> 32) & 0xFFFF0000u) : 0.f;

        A0.x = fmaf(w0, bf2f(s0.x), A0.x); A0.y = fmaf(w0, bf2f(s0.y), A0.y);
        A0.z = fmaf(w0, bf2f(s0.z), A0.z); A0.w = fmaf(w0, bf2f(s0.w), A0.w);
        A1.x = fmaf(w1, bf2f(s1.x), A1.x); A1.y = fmaf(w1, bf2f(s1.y), A1.y);
        A1.z = fmaf(w1, bf2f(s1.z), A1.z); A1.w = fmaf(w1, bf2f(s1.w), A1.w);
        A2.x = fmaf(w2, bf2f(s2.x), A2.x); A2.y = fmaf(w2, bf2f(s2.y), A2.y);
        A2.z = fmaf(w2, bf2f(s2.z), A2.z); A2.w = fmaf(w2, bf2f(s2.w), A2.w);
        A3.x = fmaf(w3, bf2f(s3.x), A3.x); A3.y = fmaf(w3, bf2f(s3.y), A3.y);
        A3.z = fmaf(w3, bf2f(s3.z), A3.z); A3.w = fmaf(w3, bf2f(s3.w), A3.w);

        int n0 = (int)((q0 >> 17) & 0x1FFFFF);
        int n1 = (int)((q1 >> 17) & 0x1FFFFF);
        int n2 = (int)((q2 >> 17) & 0x1FFFFF);
        int n3 = (int)((q3 >> 17) & 0x1FFFFF);
        e0 = (e0 >= 0 && n0 != NEXT_END) ? n0 : -1;
        e1 = (e1 >= 0 && n1 != NEXT_END) ? n1 : -1;
        e2 = (e2 >= 0 && n2 != NEXT_END) ? n2 : -1;
        e3 = (e3 >= 0 && n3 != NEXT_END) ? n3 : -1;
    }

    float4 a0, a1;
    a0.x = A0.x + A1.x; a0.y = A0.y + A1.y; a0.z = A0.z + A1.z; a0.w = A0.w + A1.w;
    a1.x = A2.x + A3.x; a1.y = A2.y + A3.y; a1.z = A2.z + A3.z; a1.w = A2.w + A3.w;

    float4* ov = reinterpret_cast<float4*>(out);
    ov[(size_t)(nb + 0) * D4 + lane] = a0;
    ov[(size_t)(nb + 1) * D4 + lane] = a1;
}

// ---------------------------------------------------------------------------
// Fallback path (ws too small): VALU gemm + atomic scatter (proven R3/R8).
// ---------------------------------------------------------------------------
__device__ __forceinline__ void fma4(float4& a, float s, const float4& b) {
    a.x = fmaf(s, b.x, a.x);
    a.y = fmaf(s, b.y, a.y);
    a.z = fmaf(s, b.z, a.z);
    a.w = fmaf(s, b.w, a.w);
}

__global__ __launch_bounds__(256) void gemm_xw(
    const float* __restrict__ x, const float* __restrict__ W,
    unsigned short* __restrict__ sup)
{
    __shared__ float4 xs[32 * D4];
    const int tid = threadIdx.x;
    const int block_row = blockIdx.x * 32;

    const float4* xv = reinterpret_cast<const float4*>(x) + (size_t)block_row * D4;
    #pragma unroll
    for (int i = 0; i < 4; ++i) xs[tid + i * 256] = xv[tid + i * 256];
    __syncthreads();

    const int cg = tid & 31;
    const int rg = tid >> 5;
    const float4* Wv = reinterpret_cast<const float4*>(W);

    float4 acc0 = {0.f, 0.f, 0.f, 0.f};
    float4 acc1 = acc0, acc2 = acc0, acc3 = acc0;

    const int r0 = rg * 4;
    #pragma unroll 8
    for (int k4 = 0; k4 < D4; ++k4) {
        float4 xa = xs[(r0 + 0) * D4 + k4];
        float4 xb = xs[(r0 + 1) * D4 + k4];
        float4 xc = xs[(r0 + 2) * D4 + k4];
        float4 xd = xs[(r0 + 3) * D4 + k4];
        float4 w0 = Wv[(k4 * 4 + 0) * D4 + cg];
        fma4(acc0, xa.x, w0); fma4(acc1, xb.x, w0);
        fma4(acc2, xc.x, w0); fma4(acc3, xd.x, w0);
        float4 w1 = Wv[(k4 * 4 + 1) * D4 + cg];
        fma4(acc0, xa.y, w1); fma4(acc1, xb.y, w1);
        fma4(acc2, xc.y, w1); fma4(acc3, xd.y, w1);
        float4 w2 = Wv[(k4 * 4 + 2) * D4 + cg];
        fma4(acc0, xa.z, w2); fma4(acc1, xb.z, w2);
        fma4(acc2, xc.z, w2); fma4(acc3, xd.z, w2);
        float4 w3 = Wv[(k4 * 4 + 3) * D4 + cg];
        fma4(acc0, xa.w, w3); fma4(acc1, xb.w, w3);
        fma4(acc2, xc.w, w3); fma4(acc3, xd.w, w3);
    }

    ushort4 p;
    #define STORE_BF16(ACC, R)                                            \
        p.x = f2bf(ACC.x); p.y = f2bf(ACC.y);                             \
        p.z = f2bf(ACC.z); p.w = f2bf(ACC.w);                             \
        *reinterpret_cast<ushort4*>(sup + (size_t)(block_row + r0 + R) * D + cg * 4) = p;
    STORE_BF16(acc0, 0)
    STORE_BF16(acc1, 1)
    STORE_BF16(acc2, 2)
    STORE_BF16(acc3, 3)
    #undef STORE_BF16
}

__global__ __launch_bounds__(256) void scatter_edges(
    const int* __restrict__ row, const int* __restrict__ col,
    const float* __restrict__ ew, const unsigned short* __restrict__ sup,
    float* __restrict__ out)
{
    const int e = blockIdx.x * 8 + (threadIdx.x >> 5);
    if (e >= N_EDGES) return;
    const int lane = threadIdx.x & 31;

    const int r = row[e];
    const int c = col[e];
    const float w = ew[e];
    ushort4 s = reinterpret_cast<const ushort4*>(sup + (size_t)c * D)[lane];
    float* o = out + (size_t)r * D + lane * 4;
    atomicAdd(o + 0, w * bf2f(s.x));
    atomicAdd(o + 1, w * bf2f(s.y));
    atomicAdd(o + 2, w * bf2f(s.z));
    atomicAdd(o + 3, w * bf2f(s.w));
}

extern "C" void kernel_launch(void* const* d_in, const int* in_sizes, int n_in,
                              void* d_out, int out_size, void* d_ws, size_t ws_size,
                              hipStream_t stream)
{
    const float* x      = (const float*)d_in[0];   // [N_NODES, 128]
    const int*   row    = (const int*)d_in[1];     // [N_EDGES]
    const int*   col    = (const int*)d_in[2];     // [N_EDGES]
    const float* ew     = (const float*)d_in[3];   // [N_EDGES]
    const float* weight = (const float*)d_in[4];   // [128, 128]
    float* out = (float*)d_out;                    // [N_NODES, 128]

    char* ws = (char*)d_ws;
    const size_t off_sup     = 0;                                      // 25.6 MB
    const size_t off_head    = off_sup + (size_t)N_NODES * D * 2;      // 800 KB (2 chains/node)
    const size_t off_entries = off_head + (((size_t)N_NODES * 8 + 15) & ~(size_t)15);
    const size_t off_wt      = off_entries + (size_t)N_EDGES * 8;      // 12.8 MB entries
    const size_t required    = off_wt + (size_t)D * D * 2;

    unsigned short* sup = (unsigned short*)(ws + off_sup);

    if (ws_size >= required) {
        int* head    = (int*)(ws + off_head);
        u64* entries = (u64*)(ws + off_entries);
        unsigned short* wt = (unsigned short*)(ws + off_wt);

        // prep: wt conversion + head = -1 (one dispatch)
        prep<<<PREP_BLOCKS, 256, 0, stream>>>(weight, wt, head);

        // block-specialized: builders (first) + MFMA gemm tiles, overlapped
        mega<<<TOTAL_BLOCKS, 256, 0, stream>>>(
            x, wt, sup, row, col, ew, head, entries);

        // gather: writes every output row (no out memset needed)
        gather_list<<<GATHER_BLOCKS, 256, 0, stream>>>(head, entries, sup, out);
    } else {
        gemm_xw<<<N_NODES / 32, 256, 0, stream>>>(x, weight, sup);
        hipMemsetAsync(d_out, 0, (size_t)N_NODES * D * sizeof(float), stream);
        scatter_edges<<<N_EDGES / 8, 256, 0, stream>>>(row, col, ew, sup, out);
    }
}